// Round 1
// baseline (97.033 us; speedup 1.0000x reference)
//
#include <hip/hip_runtime.h>
#include <hip/hip_bf16.h>
#include <stdint.h>

#define S_SCALE 30.0f
#define N_ROWS 8192
#define D_DIM 256
#define C_CLS 10000
#define C_PAD 10112   /* 79 * 128 */
#define NCB 79
#define PSTRIDE 80

typedef __attribute__((ext_vector_type(8))) short short8;
typedef __attribute__((ext_vector_type(4))) float f32x4;
typedef __attribute__((ext_vector_type(4))) unsigned short us4;

static __device__ __forceinline__ unsigned short f2bf(float f) {
  union { float f; unsigned u; } a; a.f = f;
  unsigned r = a.u + 0x7fffu + ((a.u >> 16) & 1u);
  return (unsigned short)(r >> 16);
}

static __device__ __forceinline__ void gl16(const void* g, void* l) {
  __builtin_amdgcn_global_load_lds(
      (const __attribute__((address_space(1))) void*)g,
      (__attribute__((address_space(3))) void*)l, 16, 0, 0);
}

// ---------------- row L2-normalize -> bf16, save 1/norm ----------------
__global__ __launch_bounds__(256) void k_norm(const float* __restrict__ x,
                                              unsigned short* __restrict__ xnb,
                                              float* __restrict__ inv_norm) {
  int row = blockIdx.x * 4 + (threadIdx.x >> 6);
  int l = threadIdx.x & 63;
  const float4 v = *(const float4*)(x + (size_t)row * D_DIM + l * 4);
  float ss = v.x * v.x + v.y * v.y + v.z * v.z + v.w * v.w;
#pragma unroll
  for (int m = 1; m < 64; m <<= 1) ss += __shfl_xor(ss, m, 64);
  float rn = 1.0f / sqrtf(ss);
  us4 o;
  o.x = f2bf(v.x * rn); o.y = f2bf(v.y * rn);
  o.z = f2bf(v.z * rn); o.w = f2bf(v.w * rn);
  *(us4*)(xnb + (size_t)row * D_DIM + l * 4) = o;
  if (l == 0) inv_norm[row] = rn;
}

// ---------------- W fp32 -> bf16, zero-pad rows to C_PAD ----------------
__global__ __launch_bounds__(256) void k_convw(const float* __restrict__ W,
                                               unsigned short* __restrict__ Wb) {
  int idx = blockIdx.x * 256 + threadIdx.x;   // 8 elems per thread
  size_t base = (size_t)idx * 8;
  int row = (int)(base >> 8);
  us4 o0 = {0, 0, 0, 0}, o1 = {0, 0, 0, 0};
  if (row < C_CLS) {
    const float4 a = *(const float4*)(W + base);
    const float4 b = *(const float4*)(W + base + 4);
    o0.x = f2bf(a.x); o0.y = f2bf(a.y); o0.z = f2bf(a.z); o0.w = f2bf(a.w);
    o1.x = f2bf(b.x); o1.y = f2bf(b.y); o1.z = f2bf(b.z); o1.w = f2bf(b.w);
  }
  *(us4*)(Wb + base) = o0;
  *(us4*)(Wb + base + 4) = o1;
}

// ---------------- exact fp32 target-column logit ----------------
__global__ __launch_bounds__(256) void k_tgt(const float* __restrict__ x,
                                             const float* __restrict__ W,
                                             const int* __restrict__ target,
                                             const float* __restrict__ inv_norm,
                                             float* __restrict__ tgt) {
  int row = blockIdx.x * 4 + (threadIdx.x >> 6);
  int l = threadIdx.x & 63;
  int tc = target[row];
  const float4 a = *(const float4*)(x + (size_t)row * D_DIM + l * 4);
  const float4 b = *(const float4*)(W + (size_t)tc * D_DIM + l * 4);
  float s = a.x * b.x + a.y * b.y + a.z * b.z + a.w * b.w;
#pragma unroll
  for (int m = 1; m < 64; m <<= 1) s += __shfl_xor(s, m, 64);
  if (l == 0) tgt[row] = s * inv_norm[row];
}

// ---------------- fused bf16 GEMM + exp-sum epilogue ----------------
// 128x128 tile, BK=32, double-buffered global_load_lds, 4 waves (2x2),
// each wave: 4x4 fragments of 16x16x32 MFMA.
__global__ __launch_bounds__(256, 2) void k_gemm(const unsigned short* __restrict__ xnb,
                                                 const unsigned short* __restrict__ Wb,
                                                 float* __restrict__ partials) {
  __shared__ __align__(16) char ldsA[2][8192];
  __shared__ __align__(16) char ldsB[2][8192];
  int br = blockIdx.y, bc = blockIdx.x;
  int t = threadIdx.x;
  int w = t >> 6, l = t & 63;
  int wr = w >> 1, wc = w & 1;
  const char* Ag = (const char*)xnb + (size_t)br * 128 * 512;  // 512 B/row
  const char* Bg = (const char*)Wb + (size_t)bc * 128 * 512;

  f32x4 acc[4][4];
#pragma unroll
  for (int m = 0; m < 4; m++)
#pragma unroll
    for (int n = 0; n < 4; n++) acc[m][n] = (f32x4){0.f, 0.f, 0.f, 0.f};

  auto stage = [&](int buf, int kt) {
#pragma unroll
    for (int c = 0; c < 2; ++c) {
      int p = c * 4096 + t * 16;       // linear byte in the 8 KB chunk
      int row = p >> 6;                // 64 B per row (BK=32 bf16)
      int kb = p & 63;
      size_t go = (size_t)row * 512 + (size_t)kt * 64 + kb;
      int lo = c * 4096 + w * 1024;    // wave-uniform LDS base
      gl16(Ag + go, &ldsA[buf][lo]);
      gl16(Bg + go, &ldsB[buf][lo]);
    }
  };

  auto compute = [&](int buf) {
    int lr = l & 15;
    int koff = (l >> 4) * 16;  // byte offset of this lane's 8-elem k-chunk
    short8 a[4], b[4];
#pragma unroll
    for (int m = 0; m < 4; m++)
      a[m] = *(const short8*)(ldsA[buf] + (wr * 64 + m * 16 + lr) * 64 + koff);
#pragma unroll
    for (int n = 0; n < 4; n++)
      b[n] = *(const short8*)(ldsB[buf] + (wc * 64 + n * 16 + lr) * 64 + koff);
#pragma unroll
    for (int m = 0; m < 4; m++)
#pragma unroll
      for (int n = 0; n < 4; n++)
        acc[m][n] = __builtin_amdgcn_mfma_f32_16x16x32_bf16(a[m], b[n], acc[m][n], 0, 0, 0);
  };

  stage(0, 0);
  __syncthreads();
#pragma unroll
  for (int kt = 0; kt < 8; ++kt) {
    int cur = kt & 1;
    if (kt < 7) stage(cur ^ 1, kt + 1);
    compute(cur);
    __syncthreads();
  }

  // Epilogue: exp(S*logit) masked to col<C, per-row sums.
  int lr = l & 15;
  float rs[4][4];
#pragma unroll
  for (int m = 0; m < 4; m++)
#pragma unroll
    for (int j = 0; j < 4; j++) rs[m][j] = 0.f;
#pragma unroll
  for (int n = 0; n < 4; n++) {
    int col = bc * 128 + wc * 64 + n * 16 + lr;
    bool ok = (col < C_CLS);
#pragma unroll
    for (int m = 0; m < 4; m++)
#pragma unroll
      for (int j = 0; j < 4; j++) {
        float e = ok ? __expf(S_SCALE * acc[m][n][j]) : 0.f;
        rs[m][j] += e;
      }
  }
#pragma unroll
  for (int mask = 1; mask <= 8; mask <<= 1)
#pragma unroll
    for (int m = 0; m < 4; m++)
#pragma unroll
      for (int j = 0; j < 4; j++) rs[m][j] += __shfl_xor(rs[m][j], mask, 64);

  float* rowsum = (float*)&ldsA[0][0];  // reuse LDS: [2][128] floats
  if (lr == 0) {
    int rb = (l >> 4) * 4;
#pragma unroll
    for (int m = 0; m < 4; m++)
#pragma unroll
      for (int j = 0; j < 4; j++)
        rowsum[wc * 128 + wr * 64 + m * 16 + rb + j] = rs[m][j];
  }
  __syncthreads();
  if (t < 128) {
    float s = rowsum[t] + rowsum[128 + t];
    partials[(size_t)(br * 128 + t) * PSTRIDE + bc] = s;
  }
}

// ---------------- per-row loss + block partial sums ----------------
__global__ __launch_bounds__(256) void k_loss1(const float* __restrict__ partials,
                                               const float* __restrict__ tgt,
                                               float* __restrict__ bsum) {
  __shared__ float wsum[4];
  int i = blockIdx.x * 256 + threadIdx.x;
  const float* p = partials + (size_t)i * PSTRIDE;
  float s = 0.f;
#pragma unroll
  for (int j = 0; j < NCB; ++j) s += p[j];
  float tl = tgt[i];
  float tcv = fminf(fmaxf(tl, -1.0f + 1e-7f), 1.0f - 1e-7f);
  const float cm = 0.95533648912560601964f;   // cos(0.3)
  const float sm = 0.29552020666133957510f;   // sin(0.3)
  // s*cos(acos(t)+m) = s*(t*cos m - sqrt(1-t^2)*sin m)
  float num = S_SCALE * (tcv * cm - sqrtf(fmaxf(1.0f - tcv * tcv, 0.f)) * sm);
  float sum_excl = s - __expf(S_SCALE * tl);
  float denom = __expf(num) + sum_excl;
  float L = num - __logf(denom);
#pragma unroll
  for (int m = 1; m < 64; m <<= 1) L += __shfl_xor(L, m, 64);
  int l = threadIdx.x & 63, w = threadIdx.x >> 6;
  if (l == 0) wsum[w] = L;
  __syncthreads();
  if (threadIdx.x == 0) bsum[blockIdx.x] = wsum[0] + wsum[1] + wsum[2] + wsum[3];
}

__global__ void k_loss2(const float* __restrict__ bsum, float* __restrict__ out) {
  float s = 0.f;
  for (int i = 0; i < 32; ++i) s += bsum[i];
  out[0] = -s / (float)N_ROWS;
}

// ---------------- launch ----------------
extern "C" void kernel_launch(void* const* d_in, const int* in_sizes, int n_in,
                              void* d_out, int out_size, void* d_ws, size_t ws_size,
                              hipStream_t stream) {
  const float* x = (const float*)d_in[0];
  const float* W = (const float*)d_in[1];
  const int* target = (const int*)d_in[2];
  float* out = (float*)d_out;
  char* ws = (char*)d_ws;

  unsigned short* xnb = (unsigned short*)(ws);              // 8192*256*2   = 4,194,304
  unsigned short* Wb = (unsigned short*)(ws + 4194304);     // 10112*256*2  = 5,177,344
  float* inv_norm = (float*)(ws + 9371648);                 // 8192*4
  float* tgt = (float*)(ws + 9404416);                      // 8192*4
  float* partials = (float*)(ws + 9437184);                 // 8192*80*4    = 2,621,440
  float* bsum = (float*)(ws + 12058624);                    // 32*4

  k_norm<<<2048, 256, 0, stream>>>(x, xnb, inv_norm);
  k_convw<<<1264, 256, 0, stream>>>(W, Wb);
  k_tgt<<<2048, 256, 0, stream>>>(x, W, target, inv_norm, tgt);
  k_gemm<<<dim3(79, 64), 256, 0, stream>>>(xnb, Wb, partials);
  k_loss1<<<32, 256, 0, stream>>>(partials, tgt, bsum);
  k_loss2<<<1, 1, 0, stream>>>(bsum, out);
}